// Round 3
// baseline (523.984 us; speedup 1.0000x reference)
//
#include <hip/hip_runtime.h>

#define B_  8
#define T_  4096
#define C_  1024
#define TP  4098                 // T + 2 halo rows
#define NW  (1024 * 1024)        // weights per k-slice
#define NT  48                   // K tiles: 3 shifts x (1024/64)

typedef __bf16 bf16x8 __attribute__((ext_vector_type(8)));
typedef float  f32x4  __attribute__((ext_vector_type(4)));

__device__ __forceinline__ unsigned short f2bf_rne(float f) {
    unsigned u = __float_as_uint(f);
    u += 0x7FFFu + ((u >> 16) & 1u);
    return (unsigned short)(u >> 16);
}

// async global->LDS, 16B per lane; LDS dest = wave-uniform base + lane*16
#define GLOAD16(g, l)                                                        \
    __builtin_amdgcn_global_load_lds(                                        \
        (const __attribute__((address_space(1))) void*)(g),                  \
        (__attribute__((address_space(3))) void*)(l), 16, 0, 0)

// ---------------------------------------------------------------- init
__global__ __launch_bounds__(256) void init_kernel(
    double* __restrict__ wsum, unsigned short* __restrict__ xq) {
    const int i = blockIdx.x * 256 + threadIdx.x;   // grid 64*256 = 16384
    if (i == 0) *wsum = 0.0;
    const int r16 = i >> 10;                        // 0..15 pad rows
    const int b = r16 >> 1, side = r16 & 1;
    xq[((size_t)b * TP + (size_t)side * (TP - 1)) * C_ + (i & 1023)] = 0;
}

// ---------------------------------------------------------------- fused LN stats + absmax (one x pass)
// grid 1024 blocks x 256 thr; block = 32 rows. Lane l owns cols [l*16,l*16+16)
// (disjoint per lane -> per-wave max needs no cross-lane step); 4 waves combine
// via LDS atomics; block writes a per-block partial-max row (coalesced, NO
// global atomics -- removes 1M contended cross-XCD atomicMax).
__global__ __launch_bounds__(256) void stats_absmax_kernel(
    const float* __restrict__ x, const float* __restrict__ lng,
    const float* __restrict__ lnb, float2* __restrict__ stats,
    float* __restrict__ gpart) {
    const int tid = threadIdx.x;
    const int w = tid >> 6, l = tid & 63;
    const int row0 = blockIdx.x * 32;               // b*T + t, 4096%32==0: no b-straddle
    __shared__ unsigned lmax[1024];
#pragma unroll
    for (int k = 0; k < 4; ++k) lmax[tid + k * 256] = 0u;
    __syncthreads();

    const int c0 = l * 16;
    float gv[16], bv[16], m[16];
#pragma unroll
    for (int j = 0; j < 4; ++j) {
        *(float4*)&gv[j * 4] = *(const float4*)(lng + c0 + j * 4);
        *(float4*)&bv[j * 4] = *(const float4*)(lnb + c0 + j * 4);
    }
#pragma unroll
    for (int j = 0; j < 16; ++j) m[j] = 0.0f;

#pragma unroll 2
    for (int rr = 0; rr < 8; ++rr) {
        const int row = row0 + w * 8 + rr;
        const float* xr = x + (size_t)row * C_ + c0;
        float v[16];
#pragma unroll
        for (int j = 0; j < 4; ++j) *(float4*)&v[j * 4] = *(const float4*)(xr + j * 4);
        float s = 0.0f, s2 = 0.0f;
#pragma unroll
        for (int j = 0; j < 16; ++j) { s += v[j]; s2 += v[j] * v[j]; }
#pragma unroll
        for (int off = 1; off < 64; off <<= 1) {
            s  += __shfl_xor(s,  off, 64);
            s2 += __shfl_xor(s2, off, 64);
        }
        const float mu   = s * (1.0f / C_);
        const float var  = fmaxf(s2 * (1.0f / C_) - mu * mu, 0.0f);
        const float rstd = 1.0f / sqrtf(var + 1e-5f);
        if (l == 0) stats[row] = make_float2(mu, rstd);
#pragma unroll
        for (int j = 0; j < 16; ++j)
            m[j] = fmaxf(m[j], fabsf((v[j] - mu) * rstd * gv[j] + bv[j]));
    }
    // m >= 0 so uint compare == float compare
#pragma unroll
    for (int j = 0; j < 16; ++j) atomicMax(&lmax[c0 + j], __float_as_uint(m[j]));
    __syncthreads();
#pragma unroll
    for (int k = 0; k < 4; ++k) {
        const int c = tid + k * 256;
        gpart[(size_t)blockIdx.x * 1024 + c] = __uint_as_float(lmax[c]);
    }
}

// ---------------------------------------------------------------- partials -> gamma_x[b][c]
__global__ __launch_bounds__(256) void gamma_reduce_kernel(
    const float* __restrict__ gpart, float* __restrict__ gamma_x) {
    const int c = (blockIdx.x & 3) * 256 + threadIdx.x;   // grid 32 = 8b x 4
    const int b = blockIdx.x >> 2;
    const float* p = gpart + (size_t)b * 128 * 1024 + c;  // blocks b*128..b*128+127
    float m = 0.0f;
#pragma unroll 8
    for (int i = 0; i < 128; ++i) m = fmaxf(m, p[(size_t)i * 1024]);
    gamma_x[b * 1024 + c] = m;
}

// ---------------------------------------------------------------- sum |W|
__global__ __launch_bounds__(256) void wsum_kernel(
    const float* __restrict__ W, double* __restrict__ wsum) {
    size_t i = ((size_t)blockIdx.x * 256 + threadIdx.x) * 8;  // grid 1536
    float4 a  = *(const float4*)(W + i);
    float4 b4 = *(const float4*)(W + i + 4);
    float s = fabsf(a.x) + fabsf(a.y) + fabsf(a.z) + fabsf(a.w)
            + fabsf(b4.x) + fabsf(b4.y) + fabsf(b4.z) + fabsf(b4.w);
#pragma unroll
    for (int off = 32; off > 0; off >>= 1) s += __shfl_down(s, off, 64);
    __shared__ float ps[4];
    const int wave = threadIdx.x >> 6, lane = threadIdx.x & 63;
    if (lane == 0) ps[wave] = s;
    __syncthreads();
    if (threadIdx.x == 0) atomicAdd(wsum, (double)((ps[0] + ps[1]) + (ps[2] + ps[3])));
}

// ---------------------------------------------------------------- weight quant + repack wq[k][o][i]
__global__ __launch_bounds__(256) void wquant_kernel(
    const float* __restrict__ W, const double* __restrict__ wsum,
    unsigned short* __restrict__ wq, float* __restrict__ beta_out) {
    const int gid = blockIdx.x * 256 + threadIdx.x;   // (o,i) pair, grid 4096
    const float beta = fmaxf((float)(*wsum * (1.0 / 3145728.0)), 1e-5f);
    if (gid == 0) *beta_out = beta;
    const float* wp = W + (size_t)gid * 3;
#pragma unroll
    for (int k = 0; k < 3; ++k) {
        float s  = wp[k] / beta;                      // ref: clip then round
        float r  = rintf(fminf(fmaxf(s, -1.0f), 1.0f));
        wq[(size_t)k * NW + gid] = f2bf_rne(r);       // {-1,0,1} exact in bf16
    }
}

// ---------------------------------------------------------------- activation quant -> padded xq
__device__ __forceinline__ unsigned short quant1(float xv, float2 s, float g,
                                                 float be, float gam) {
    float xn = (xv - s.x) * s.y * g + be;
    float sc = 127.0f / fmaxf(gam, 1e-5f);
    float r  = rintf(xn * sc);                        // ref: round then clip
    r = fminf(fmaxf(r, -127.0f), 127.0f);
    return f2bf_rne(r);                               // integer |r|<=127: exact
}

__global__ __launch_bounds__(256) void xquant_kernel(
    const float* __restrict__ x, const float2* __restrict__ stats,
    const float* __restrict__ lng, const float* __restrict__ lnb,
    const float* __restrict__ gamma_x, unsigned short* __restrict__ xq) {
    const int row = blockIdx.x;                       // b*T + t, grid 32768
    const int b = row >> 12, t = row & 4095;
    const float2 s = stats[row];
    const int c = threadIdx.x * 4;
    float4 xv = *(const float4*)(x + (size_t)row * C_ + c);
    float4 gv = *(const float4*)(lng + c);
    float4 bv = *(const float4*)(lnb + c);
    float4 gm = *(const float4*)(gamma_x + b * C_ + c);
    ushort4 qv;
    qv.x = quant1(xv.x, s, gv.x, bv.x, gm.x);
    qv.y = quant1(xv.y, s, gv.y, bv.y, gm.y);
    qv.z = quant1(xv.z, s, gv.z, bv.z, gm.z);
    qv.w = quant1(xv.w, s, gv.w, bv.w, gm.w);
    *(ushort4*)(xq + ((size_t)b * TP + t + 1) * C_ + c) = qv;
}

// ---------------------------------------------------------------- conv-as-GEMM: 256x256 tile, 8-wave,
// 4-phase/K-tile, SINGLE barrier per phase. All LDS fragment reads are issued one
// phase EARLY: af-reload interleaved after each 4-MFMA group (progressive single-
// buffer reload -> no extra VGPRs), bf-reload post-MFMA on k-transition phases.
// lgkmcnt(0) at phase start waits reads issued last phase (already latency-hidden
// under the MFMA cluster) -> LDS pipe and MFMA pipe overlap instead of alternating.
// Counted vmcnt: VM6 at P0/P2 steady (retire ledger in comments), VM6/VM4/VM0 tail.
__global__ __launch_bounds__(512, 2) void gemm_kernel(
    const unsigned short* __restrict__ xq,   // [B][TP][C] bf16 (padded)
    const unsigned short* __restrict__ wq,   // [3][O][I] bf16 ternary
    const float* __restrict__ gamma_x,       // [B][C]
    const float* __restrict__ beta_p,        // scalar
    float* __restrict__ out) {               // [B][T][O] fp32
    __shared__ __align__(16) unsigned short sA[2][2][8192];  // 64 KiB
    __shared__ __align__(16) unsigned short sB[2][2][8192];  // 64 KiB

    const int tid = threadIdx.x;
    const int w   = tid >> 6;                 // wave 0..7 (2M x 4N)
    const int l   = tid & 63;
    const int q   = l >> 4;                   // k-granule 0..3
    const int lr  = l & 15;                   // fragment row
    const int g8    = (q ^ ((lr >> 1) & 3)) * 8;           // read granule (swizzled)
    const int srcg8 = ((l & 3) ^ ((l >> 3) & 3)) * 8;      // stage src granule (same involution)

    // XCD-bijective decode: 512 blocks = 8 xcd-slots x 64; 4 n-tiles of one
    // (b,mt) A-panel share an XCD-slot (L2 reuse of A).
    const int d  = blockIdx.x;
    const int gg = (d & 7) + ((d >> 5) << 3);   // (b,mt) group 0..127
    const int nt = (d >> 3) & 3;
    const int b  = gg >> 4;
    const int t0 = (gg & 15) << 8;
    const int n0 = nt << 8;

    const int wm = (w >> 2) * 128;            // wave M offset (2 x 128)
    const int wn = (w & 3) * 64;              // wave N offset (4 x 64)

    const unsigned short* A0 = xq + (size_t)(b * TP + t0) * C_;
    const unsigned short* Bq = wq + (size_t)n0 * C_;

    f32x4 acc[8][4] = {};
    bf16x8 af[4], bf[4];

#define RD_A(MI, ABU, AKH, AMS)                                                   \
    af[MI] = *(const bf16x8*)&sA[ABU][AKH][(wm + (AMS) * 64 + (MI) * 16 + lr) * 32 + g8]
#define RD_B_ALL(BBU, BKH) do {                                                   \
        _Pragma("unroll")                                                         \
        for (int ni = 0; ni < 4; ++ni)                                            \
            bf[ni] = *(const bf16x8*)&sB[BBU][BKH][(wn + ni * 16 + lr) * 32 + g8];\
    } while (0)

#define STG(DST, GP) do {                                                         \
        GLOAD16((GP) + (size_t)(w * 16 + (l >> 2)) * C_ + srcg8, (DST) + w * 512);\
        GLOAD16((GP) + (size_t)(w * 16 + (l >> 2) + 128) * C_ + srcg8,            \
                (DST) + 4096 + w * 512);                                          \
    } while (0)
#define STG_A(S, KH) STG(&sA[(S) & 1][KH][0], A0 + (S) * 64 + (KH) * 32)
#define STG_B(S, KH) STG(&sB[(S) & 1][KH][0],                                     \
        Bq + (size_t)((S) >> 4) * NW + ((S) & 15) * 64 + (KH) * 32)

#define VM8 asm volatile("s_waitcnt vmcnt(8)" ::: "memory")
#define VM6 asm volatile("s_waitcnt vmcnt(6)" ::: "memory")
#define VM4 asm volatile("s_waitcnt vmcnt(4)" ::: "memory")
#define VM0 asm volatile("s_waitcnt vmcnt(0)" ::: "memory")
#define VMX do {} while (0)

// phase: [stage issue][wait prev reads][MFMA x16 with af-reload interleaved]
//        [bf-reload][vm][barrier]
#define PH(AM, DOAF, ABU, AMS, AKH, DOBF, BBU, BKH, STGC, VMC, BAR) do {          \
        STGC;                                                                     \
        asm volatile("s_waitcnt lgkmcnt(0)" ::: "memory");                        \
        __builtin_amdgcn_sched_barrier(0);                                        \
        __builtin_amdgcn_s_setprio(1);                                            \
        _Pragma("unroll")                                                         \
        for (int mi = 0; mi < 4; ++mi) {                                          \
            _Pragma("unroll")                                                     \
            for (int ni = 0; ni < 4; ++ni)                                        \
                acc[(AM) * 4 + mi][ni] = __builtin_amdgcn_mfma_f32_16x16x32_bf16( \
                    af[mi], bf[ni], acc[(AM) * 4 + mi][ni], 0, 0, 0);             \
            if (DOAF) { RD_A(mi, ABU, AKH, AMS); }                                \
            __builtin_amdgcn_sched_barrier(0);                                    \
        }                                                                         \
        __builtin_amdgcn_s_setprio(0);                                            \
        if (DOBF) { RD_B_ALL(BBU, BKH); }                                         \
        VMC;                                                                      \
        if (BAR) { __builtin_amdgcn_s_barrier();                                  \
                   __builtin_amdgcn_sched_barrier(0); }                           \
    } while (0)

// P0: mfma m0/k0, af->m1 k0, VM6 (retires (kt,k1) staged slab)
// P1: mfma m1/k0, af->m0 k1, bf->k1
// P2: mfma m0/k1, af->m1 k1, VM6 (retires (kt+1,k0) staged slab)
// P3: mfma m1/k1, af->next-buf m0 k0, bf->next-buf k0
#define TILE(BU, S0C, S1C, S2C, S3C, VA, VB, AF3, BF3, BAR3) do {                 \
        PH(0, 1, BU, 1, 0, 0, 0, 0, S0C, VA, 1);                                  \
        PH(1, 1, BU, 0, 1, 1, BU, 1, S1C, VMX, 1);                                \
        PH(0, 1, BU, 1, 1, 0, 0, 0, S2C, VB, 1);                                  \
        PH(1, AF3, (BU) ^ 1, 0, 0, BF3, (BU) ^ 1, 0, S3C, VMX, BAR3);             \
    } while (0)

#define TILE_ST(KT, BU)                                                           \
    TILE(BU, { STG_A((KT) + 1, 1); }, { STG_B((KT) + 1, 1); },                    \
             { STG_A((KT) + 2, 0); }, { STG_B((KT) + 2, 0); }, VM6, VM6, 1, 1, 1)

    // prologue: tile0 (k0,k1) + tile1.k0 = 12 loads; VM8 -> tile0.k0 landed
    STG_A(0, 0); STG_B(0, 0);
    STG_A(0, 1); STG_B(0, 1);
    STG_A(1, 0); STG_B(1, 0);
    VM8;
    __builtin_amdgcn_s_barrier();
    __builtin_amdgcn_sched_barrier(0);
    RD_A(0, 0, 0, 0); RD_A(1, 0, 0, 0); RD_A(2, 0, 0, 0); RD_A(3, 0, 0, 0);
    RD_B_ALL(0, 0);

#pragma unroll 1
    for (int kt = 0; kt < 46; kt += 2) {
        TILE_ST(kt, 0);
        TILE_ST(kt + 1, 1);
    }
    // tail: tile 46 stages only (47,k1); tile 47 stages nothing
    TILE(0, { STG_A(47, 1); }, { STG_B(47, 1); }, {}, {}, VM6, VM4, 1, 1, 1);
    TILE(1, {}, {}, {}, {}, VM0, VMX, 0, 0, 0);

    // epilogue: y = acc * beta * gamma_x[b,o] / 127  (C/D: col=lane&15, row=quad*4+reg)
    const float beta = *beta_p;
#pragma unroll
    for (int ni = 0; ni < 4; ++ni) {
        const int o = n0 + wn + ni * 16 + lr;
        const float sc = beta * fmaxf(gamma_x[b * C_ + o], 1e-5f) * (1.0f / 127.0f);
#pragma unroll
        for (int mi = 0; mi < 8; ++mi) {
#pragma unroll
            for (int r = 0; r < 4; ++r) {
                const int t = t0 + wm + mi * 16 + q * 4 + r;
                out[(size_t)(b * T_ + t) * C_ + o] = acc[mi][ni][r] * sc;
            }
        }
    }
#undef RD_A
#undef RD_B_ALL
#undef STG
#undef STG_A
#undef STG_B
#undef PH
#undef TILE
#undef TILE_ST
}

// ---------------------------------------------------------------- launch
extern "C" void kernel_launch(void* const* d_in, const int* in_sizes, int n_in,
                              void* d_out, int out_size, void* d_ws, size_t ws_size,
                              hipStream_t stream) {
    const float* x   = (const float*)d_in[0];  // [8,4096,1024] fp32
    const float* lng = (const float*)d_in[1];  // [1024] fp32
    const float* lnb = (const float*)d_in[2];  // [1024] fp32
    const float* W   = (const float*)d_in[3];  // [1024,1024,3] fp32
    float* out = (float*)d_out;                // fp32 output [8,4096,1024]

    char* ws = (char*)d_ws;
    float2*         stats  = (float2*)(ws + 0);          //   262144 B
    float*          gamma  = (float*) (ws + 262144);     //    32768 B
    double*         wsum   = (double*)(ws + 294912);     //        8 B
    float*          beta   = (float*) (ws + 294920);     //        4 B (+pad)
    unsigned short* wq     = (unsigned short*)(ws + 294928);   // 6291456 B
    unsigned short* xq     = (unsigned short*)(ws + 6586384);  // 67141632 B -> 73.7 MB total
    float*          gpart  = out;              // [1024][1024] scratch; gemm overwrites out later

    init_kernel        <<<64,    256, 0, stream>>>(wsum, xq);
    stats_absmax_kernel<<<1024,  256, 0, stream>>>(x, lng, lnb, stats, gpart);
    gamma_reduce_kernel<<<32,    256, 0, stream>>>(gpart, gamma);
    wsum_kernel        <<<1536,  256, 0, stream>>>(W, wsum);
    wquant_kernel      <<<4096,  256, 0, stream>>>(W, wsum, wq, beta);
    xquant_kernel      <<<32768, 256, 0, stream>>>(x, stats, lng, lnb, gamma, xq);
    gemm_kernel        <<<dim3(512), 512, 0, stream>>>(xq, wq, gamma, beta, out);
}

// Round 4
// 520.898 us; speedup vs baseline: 1.0059x; 1.0059x over previous
//
#include <hip/hip_runtime.h>

#define B_  8
#define T_  4096
#define C_  1024
#define TP  4098                 // T + 2 halo rows
#define NW  (1024 * 1024)        // weights per k-slice

typedef __bf16 bf16x8 __attribute__((ext_vector_type(8)));
typedef float  f32x4  __attribute__((ext_vector_type(4)));

__device__ __forceinline__ unsigned short f2bf_rne(float f) {
    unsigned u = __float_as_uint(f);
    u += 0x7FFFu + ((u >> 16) & 1u);
    return (unsigned short)(u >> 16);
}

// async global->LDS, 16B per lane; LDS dest = wave-uniform base + lane*16
#define GLOAD16(g, l)                                                        \
    __builtin_amdgcn_global_load_lds(                                        \
        (const __attribute__((address_space(1))) void*)(g),                  \
        (__attribute__((address_space(3))) void*)(l), 16, 0, 0)

// ---------------------------------------------------------------- init (zero xq halo rows)
__global__ __launch_bounds__(256) void init_kernel(unsigned short* __restrict__ xq) {
    const int i = blockIdx.x * 256 + threadIdx.x;   // grid 64*256 = 16384
    const int r16 = i >> 10;                        // 0..15 pad rows
    const int b = r16 >> 1, side = r16 & 1;
    xq[((size_t)b * TP + (size_t)side * (TP - 1)) * C_ + (i & 1023)] = 0;
}

// ---------------------------------------------------------------- fused LN stats + absmax (one x pass)
__global__ __launch_bounds__(256) void stats_absmax_kernel(
    const float* __restrict__ x, const float* __restrict__ lng,
    const float* __restrict__ lnb, float2* __restrict__ stats,
    float* __restrict__ gpart) {
    const int tid = threadIdx.x;
    const int w = tid >> 6, l = tid & 63;
    const int row0 = blockIdx.x * 32;               // b*T + t, 4096%32==0: no b-straddle
    __shared__ unsigned lmax[1024];
#pragma unroll
    for (int k = 0; k < 4; ++k) lmax[tid + k * 256] = 0u;
    __syncthreads();

    const int c0 = l * 16;
    float gv[16], bv[16], m[16];
#pragma unroll
    for (int j = 0; j < 4; ++j) {
        *(float4*)&gv[j * 4] = *(const float4*)(lng + c0 + j * 4);
        *(float4*)&bv[j * 4] = *(const float4*)(lnb + c0 + j * 4);
    }
#pragma unroll
    for (int j = 0; j < 16; ++j) m[j] = 0.0f;

#pragma unroll 2
    for (int rr = 0; rr < 8; ++rr) {
        const int row = row0 + w * 8 + rr;
        const float* xr = x + (size_t)row * C_ + c0;
        float v[16];
#pragma unroll
        for (int j = 0; j < 4; ++j) *(float4*)&v[j * 4] = *(const float4*)(xr + j * 4);
        float s = 0.0f, s2 = 0.0f;
#pragma unroll
        for (int j = 0; j < 16; ++j) { s += v[j]; s2 += v[j] * v[j]; }
#pragma unroll
        for (int off = 1; off < 64; off <<= 1) {
            s  += __shfl_xor(s,  off, 64);
            s2 += __shfl_xor(s2, off, 64);
        }
        const float mu   = s * (1.0f / C_);
        const float var  = fmaxf(s2 * (1.0f / C_) - mu * mu, 0.0f);
        const float rstd = 1.0f / sqrtf(var + 1e-5f);
        if (l == 0) stats[row] = make_float2(mu, rstd);
#pragma unroll
        for (int j = 0; j < 16; ++j)
            m[j] = fmaxf(m[j], fabsf((v[j] - mu) * rstd * gv[j] + bv[j]));
    }
    // m >= 0 so uint compare == float compare
#pragma unroll
    for (int j = 0; j < 16; ++j) atomicMax(&lmax[c0 + j], __float_as_uint(m[j]));
    __syncthreads();
#pragma unroll
    for (int k = 0; k < 4; ++k) {
        const int c = tid + k * 256;
        gpart[(size_t)blockIdx.x * 1024 + c] = __uint_as_float(lmax[c]);
    }
}

// ---------------------------------------------------------------- partials -> gamma_x[b][c]
__global__ __launch_bounds__(256) void gamma_reduce_kernel(
    const float* __restrict__ gpart, float* __restrict__ gamma_x) {
    const int c = (blockIdx.x & 3) * 256 + threadIdx.x;   // grid 32 = 8b x 4
    const int b = blockIdx.x >> 2;
    const float* p = gpart + (size_t)b * 128 * 1024 + c;  // blocks b*128..b*128+127
    float m = 0.0f;
#pragma unroll 8
    for (int i = 0; i < 128; ++i) m = fmaxf(m, p[(size_t)i * 1024]);
    gamma_x[b * 1024 + c] = m;
}

// ---------------------------------------------------------------- sum |W| partials (NO global atomics)
__global__ __launch_bounds__(256) void wsum_kernel(
    const float* __restrict__ W, float* __restrict__ wpart) {
    size_t i = ((size_t)blockIdx.x * 256 + threadIdx.x) * 8;  // grid 1536
    float4 a  = *(const float4*)(W + i);
    float4 b4 = *(const float4*)(W + i + 4);
    float s = fabsf(a.x) + fabsf(a.y) + fabsf(a.z) + fabsf(a.w)
            + fabsf(b4.x) + fabsf(b4.y) + fabsf(b4.z) + fabsf(b4.w);
#pragma unroll
    for (int off = 32; off > 0; off >>= 1) s += __shfl_down(s, off, 64);
    __shared__ float ps[4];
    const int wave = threadIdx.x >> 6, lane = threadIdx.x & 63;
    if (lane == 0) ps[wave] = s;
    __syncthreads();
    if (threadIdx.x == 0) wpart[blockIdx.x] = (ps[0] + ps[1]) + (ps[2] + ps[3]);
}

// ---------------------------------------------------------------- 1-block fp64 reduce of wpart[1536]
__global__ __launch_bounds__(256) void wsum_reduce_kernel(
    const float* __restrict__ wpart, double* __restrict__ wsum) {
    double s = 0.0;
    for (int i = threadIdx.x; i < 1536; i += 256) s += (double)wpart[i];
#pragma unroll
    for (int off = 32; off > 0; off >>= 1) s += __shfl_down(s, off, 64);
    __shared__ double ps[4];
    const int wave = threadIdx.x >> 6, lane = threadIdx.x & 63;
    if (lane == 0) ps[wave] = s;
    __syncthreads();
    if (threadIdx.x == 0) *wsum = (ps[0] + ps[1]) + (ps[2] + ps[3]);
}

// ---------------------------------------------------------------- weight quant + repack wq[k][o][i]
__global__ __launch_bounds__(256) void wquant_kernel(
    const float* __restrict__ W, const double* __restrict__ wsum,
    unsigned short* __restrict__ wq, float* __restrict__ beta_out) {
    const int gid = blockIdx.x * 256 + threadIdx.x;   // (o,i) pair, grid 4096
    const float beta = fmaxf((float)(*wsum * (1.0 / 3145728.0)), 1e-5f);
    if (gid == 0) *beta_out = beta;
    const float* wp = W + (size_t)gid * 3;
#pragma unroll
    for (int k = 0; k < 3; ++k) {
        float s  = wp[k] / beta;                      // ref: clip then round
        float r  = rintf(fminf(fmaxf(s, -1.0f), 1.0f));
        wq[(size_t)k * NW + gid] = f2bf_rne(r);       // {-1,0,1} exact in bf16
    }
}

// ---------------------------------------------------------------- activation quant -> padded xq (4 rows/block)
__device__ __forceinline__ unsigned short quant1s(float xv, float2 s, float g,
                                                  float be, float sc) {
    float xn = (xv - s.x) * s.y * g + be;
    float r  = rintf(xn * sc);                        // ref: round then clip
    r = fminf(fmaxf(r, -127.0f), 127.0f);
    return f2bf_rne(r);                               // integer |r|<=127: exact
}

__global__ __launch_bounds__(256) void xquant_kernel(
    const float* __restrict__ x, const float2* __restrict__ stats,
    const float* __restrict__ lng, const float* __restrict__ lnb,
    const float* __restrict__ gamma_x, unsigned short* __restrict__ xq) {
    const int r0 = blockIdx.x * 4;                    // grid 8192; 4 rows share b
    const int b = r0 >> 12;
    const int c = threadIdx.x * 4;
    float4 gv = *(const float4*)(lng + c);
    float4 bv = *(const float4*)(lnb + c);
    float4 gm = *(const float4*)(gamma_x + b * C_ + c);
    float4 sc;
    sc.x = 127.0f / fmaxf(gm.x, 1e-5f);
    sc.y = 127.0f / fmaxf(gm.y, 1e-5f);
    sc.z = 127.0f / fmaxf(gm.z, 1e-5f);
    sc.w = 127.0f / fmaxf(gm.w, 1e-5f);
#pragma unroll
    for (int rr = 0; rr < 4; ++rr) {
        const int row = r0 + rr, t = row & 4095;
        const float2 s = stats[row];
        float4 xv = *(const float4*)(x + (size_t)row * C_ + c);
        ushort4 qv;
        qv.x = quant1s(xv.x, s, gv.x, bv.x, sc.x);
        qv.y = quant1s(xv.y, s, gv.y, bv.y, sc.y);
        qv.z = quant1s(xv.z, s, gv.z, bv.z, sc.z);
        qv.w = quant1s(xv.w, s, gv.w, bv.w, sc.w);
        *(ushort4*)(xq + ((size_t)b * TP + t + 1) * C_ + c) = qv;
    }
}

// ---------------------------------------------------------------- conv-as-GEMM: 256x256 tile, 8-wave.
// MERGED phases: 96 phases of 32 MFMA (one k-half x all 8 m-frags). Rolling af[4]
// window: groups 0-3 consume m0-m3 / reload m4-m7 (current slab); groups 4-7
// consume m4-m7 / reload m0-m3 (NEXT slab) behind lgkmcnt(3) partial waits.
// Staging depth 3 half-slabs, VM4 per phase (end of phase h leaves only slab h+3
// in flight -> slab h+2 landed+barriered one full phase before its reads).
// Slots: slab h -> sA/sB[(h>>1)&1][h&1]; write (h+3)&3 disjoint from reads
// {h&3,(h+1)&3}. One barrier per 32 MFMA. Swizzle/XCD decode as proven (r2/r3).
__global__ __launch_bounds__(512, 2) void gemm_kernel(
    const unsigned short* __restrict__ xq,   // [B][TP][C] bf16 (padded)
    const unsigned short* __restrict__ wq,   // [3][O][I] bf16 ternary
    const float* __restrict__ gamma_x,       // [B][C]
    const float* __restrict__ beta_p,        // scalar
    float* __restrict__ out) {               // [B][T][O] fp32
    __shared__ __align__(16) unsigned short sA[2][2][8192];  // 64 KiB
    __shared__ __align__(16) unsigned short sB[2][2][8192];  // 64 KiB

    const int tid = threadIdx.x;
    const int w   = tid >> 6;                 // wave 0..7 (2M x 4N)
    const int l   = tid & 63;
    const int q   = l >> 4;                   // k-granule 0..3
    const int lr  = l & 15;                   // fragment row
    const int g8    = (q ^ ((lr >> 1) & 3)) * 8;           // read granule (swizzled)
    const int srcg8 = ((l & 3) ^ ((l >> 3) & 3)) * 8;      // stage src granule (same involution)

    // XCD-bijective decode: 512 blocks = 8 xcd-slots x 64; 4 n-tiles of one
    // (b,mt) A-panel share an XCD-slot (L2 reuse of A).
    const int d  = blockIdx.x;
    const int gg = (d & 7) + ((d >> 5) << 3);   // (b,mt) group 0..127
    const int nt = (d >> 3) & 3;
    const int b  = gg >> 4;
    const int t0 = (gg & 15) << 8;
    const int n0 = nt << 8;

    const int wm = (w >> 2) * 128;            // wave M offset (2 x 128)
    const int wn = (w & 3) * 64;              // wave N offset (4 x 64)

    const unsigned short* A0 = xq + (size_t)(b * TP + t0) * C_;
    const unsigned short* Bq = wq + (size_t)n0 * C_;

    f32x4 acc[8][4] = {};
    bf16x8 af[4], bf[4];

#define RDA(I, BU2, KH2, MI)                                                      \
    af[I] = *(const bf16x8*)&sA[BU2][KH2][(wm + (MI) * 16 + lr) * 32 + g8]
#define RDB(BU2, KH2) do {                                                        \
        _Pragma("unroll")                                                         \
        for (int ni = 0; ni < 4; ++ni)                                            \
            bf[ni] = *(const bf16x8*)&sB[BU2][KH2][(wn + ni * 16 + lr) * 32 + g8];\
    } while (0)

    // stage half-slab S (A elem offset = S*32; B: shift=S>>5, i0=((S>>1)&15)*64+(S&1)*32)
#define STG_AB(S) do {                                                            \
        unsigned short* dA = &sA[((S) >> 1) & 1][(S) & 1][0];                     \
        unsigned short* dB = &sB[((S) >> 1) & 1][(S) & 1][0];                     \
        const unsigned short* gA = A0 + (size_t)(S) * 32;                         \
        const unsigned short* gB = Bq + (size_t)((S) >> 5) * NW                   \
            + ((((S) >> 1) & 15) * 64 + ((S) & 1) * 32);                          \
        GLOAD16(gA + (size_t)(w * 16 + (l >> 2)) * C_ + srcg8, dA + w * 512);     \
        GLOAD16(gA + (size_t)(w * 16 + (l >> 2) + 128) * C_ + srcg8,              \
                dA + 4096 + w * 512);                                             \
        GLOAD16(gB + (size_t)(w * 16 + (l >> 2)) * C_ + srcg8, dB + w * 512);     \
        GLOAD16(gB + (size_t)(w * 16 + (l >> 2) + 128) * C_ + srcg8,              \
                dB + 4096 + w * 512);                                             \
    } while (0)

#define VM4 asm volatile("s_waitcnt vmcnt(4)" ::: "memory")
#define VM0 asm volatile("s_waitcnt vmcnt(0)" ::: "memory")
#define VMX do {} while (0)
#define LGKM0 do { asm volatile("s_waitcnt lgkmcnt(0)" ::: "memory");             \
                   __builtin_amdgcn_sched_barrier(0); } while (0)
#define LGKM3 do { asm volatile("s_waitcnt lgkmcnt(3)" ::: "memory");             \
                   __builtin_amdgcn_sched_barrier(0); } while (0)

#define GRP(G, RELOAD) do {                                                       \
        _Pragma("unroll")                                                         \
        for (int ni = 0; ni < 4; ++ni)                                            \
            acc[G][ni] = __builtin_amdgcn_mfma_f32_16x16x32_bf16(                 \
                af[(G) & 3], bf[ni], acc[G][ni], 0, 0, 0);                        \
        RELOAD;                                                                   \
        __builtin_amdgcn_sched_barrier(0);                                        \
    } while (0)

// one merged phase: current slab (CB,CK), next slab (NB,NK); DONXT=0 only at h=95
#define PHM(CB, CK, NB, NK, STGC, VMC, DOBAR, DONXT) do {                         \
        STGC;                                                                     \
        LGKM0;                                                                    \
        __builtin_amdgcn_s_setprio(1);                                            \
        GRP(0, { RDA(0, CB, CK, 4); });                                           \
        GRP(1, { RDA(1, CB, CK, 5); });                                           \
        GRP(2, { RDA(2, CB, CK, 6); });                                           \
        GRP(3, { RDA(3, CB, CK, 7); });                                           \
        LGKM3;                                                                    \
        GRP(4, { if (DONXT) { RDA(0, NB, NK, 0); } });                            \
        LGKM3;                                                                    \
        GRP(5, { if (DONXT) { RDA(1, NB, NK, 1); } });                            \
        LGKM3;                                                                    \
        GRP(6, { if (DONXT) { RDA(2, NB, NK, 2); } });                            \
        LGKM3;                                                                    \
        GRP(7, { if (DONXT) { RDA(3, NB, NK, 3); } });                            \
        __builtin_amdgcn_s_setprio(0);                                            \
        if (DONXT) { RDB(NB, NK); }                                               \
        VMC;                                                                      \
        if (DOBAR) { __builtin_amdgcn_s_barrier();                                \
                     __builtin_amdgcn_sched_barrier(0); }                         \
    } while (0)

    // prologue: stage slabs 0,1,2 (12 loads); VM4 -> slabs 0,1 landed; preload frags
    STG_AB(0); STG_AB(1); STG_AB(2);
    VM4;
    __builtin_amdgcn_s_barrier();
    __builtin_amdgcn_sched_barrier(0);
    RDA(0, 0, 0, 0); RDA(1, 0, 0, 1); RDA(2, 0, 0, 2); RDA(3, 0, 0, 3);
    RDB(0, 0);

    // phases h=0..91 (23 iters x 4), slots cycle (0,0)(0,1)(1,0)(1,1); stage h+3
#pragma unroll 1
    for (int it = 0; it < 23; ++it) {
        const int s3 = it * 4 + 3;
        PHM(0, 0, 0, 1, { STG_AB(s3);     }, VM4, 1, 1);
        PHM(0, 1, 1, 0, { STG_AB(s3 + 1); }, VM4, 1, 1);
        PHM(1, 0, 1, 1, { STG_AB(s3 + 2); }, VM4, 1, 1);
        PHM(1, 1, 0, 0, { STG_AB(s3 + 3); }, VM4, 1, 1);
    }
    // h=92: stage 95 | h=93: drain | h=94 reads slab95 | h=95: tail (no next)
    PHM(0, 0, 0, 1, { STG_AB(95); }, VM4, 1, 1);
    PHM(0, 1, 1, 0, {;},             VM0, 1, 1);
    PHM(1, 0, 1, 1, {;},             VMX, 1, 1);
    PHM(1, 1, 0, 0, {;},             VMX, 0, 0);

    // epilogue: y = acc * beta * gamma_x[b,o] / 127  (C/D: col=lane&15, row=quad*4+reg)
    const float beta = *beta_p;
#pragma unroll
    for (int ni = 0; ni < 4; ++ni) {
        const int o = n0 + wn + ni * 16 + lr;
        const float sc = beta * fmaxf(gamma_x[b * C_ + o], 1e-5f) * (1.0f / 127.0f);
#pragma unroll
        for (int mi = 0; mi < 8; ++mi) {
#pragma unroll
            for (int r = 0; r < 4; ++r) {
                const int t = t0 + wm + mi * 16 + q * 4 + r;
                out[(size_t)(b * T_ + t) * C_ + o] = acc[mi][ni][r] * sc;
            }
        }
    }
#undef RDA
#undef RDB
#undef STG_AB
#undef PHM
#undef GRP
}

// ---------------------------------------------------------------- launch
extern "C" void kernel_launch(void* const* d_in, const int* in_sizes, int n_in,
                              void* d_out, int out_size, void* d_ws, size_t ws_size,
                              hipStream_t stream) {
    const float* x   = (const float*)d_in[0];  // [8,4096,1024] fp32
    const float* lng = (const float*)d_in[1];  // [1024] fp32
    const float* lnb = (const float*)d_in[2];  // [1024] fp32
    const float* W   = (const float*)d_in[3];  // [1024,1024,3] fp32
    float* out = (float*)d_out;                // fp32 output [8,4096,1024]

    char* ws = (char*)d_ws;
    float2*         stats  = (float2*)(ws + 0);          //   262144 B
    float*          gamma  = (float*) (ws + 262144);     //    32768 B
    double*         wsum   = (double*)(ws + 294912);     //        8 B
    float*          beta   = (float*) (ws + 294920);     //        4 B (+pad)
    unsigned short* wq     = (unsigned short*)(ws + 294928);   // 6291456 B
    unsigned short* xq     = (unsigned short*)(ws + 6586384);  // 67141632 B -> 73.7 MB total
    float*          gpart  = out;              // [1024][1024] scratch (gemm overwrites out)
    float*          wpart  = out + 2 * 1024 * 1024;  // 1536 floats, clear of gpart

    init_kernel        <<<64,    256, 0, stream>>>(xq);
    stats_absmax_kernel<<<1024,  256, 0, stream>>>(x, lng, lnb, stats, gpart);
    gamma_reduce_kernel<<<32,    256, 0, stream>>>(gpart, gamma);
    wsum_kernel        <<<1536,  256, 0, stream>>>(W, wpart);
    wsum_reduce_kernel <<<1,     256, 0, stream>>>(wpart, wsum);
    wquant_kernel      <<<4096,  256, 0, stream>>>(W, wsum, wq, beta);
    xquant_kernel      <<<8192,  256, 0, stream>>>(x, stats, lng, lnb, gamma, xq);
    gemm_kernel        <<<dim3(512), 512, 0, stream>>>(xq, wq, gamma, beta, out);
}